// Round 1
// baseline (150.399 us; speedup 1.0000x reference)
//
#include <hip/hip_runtime.h>

#define N_POINTS  131072
#define N_ANCHORS 2048
#define CHUNKS    4
#define M_PER     (N_ANCHORS / CHUNKS)   // 512
#define LOG2E     1.4426950408889634f

// ---------------------------------------------------------------------------
// Kernel 1: per-anchor parameter folding.
//   s  = 1/(2 w^2)                 (positive)
//   sp = -s * log2(e)              (negative; base-2 exponent scale)
//   arg(n,m) = sp*|x|^2 + q_m + r_m . x_n   with  q = sp*|a|^2, r = -2*sp*a
//   K = exp2(min(arg,0));  min matches reference's max(sqdist,0) clamp.
// Packed as float4 (r0,r1,r2,q) + float2 (sp, coeff) for scalar-load friendliness.
// ---------------------------------------------------------------------------
__global__ void precompute_anchors(const float* __restrict__ aloc,
                                   const float* __restrict__ coeffs,
                                   const float* __restrict__ params,
                                   float4* __restrict__ A4,
                                   float2* __restrict__ A2) {
    int m = blockIdx.x * blockDim.x + threadIdx.x;
    if (m >= N_ANCHORS) return;
    float a0 = aloc[3 * m + 0];
    float a1 = aloc[3 * m + 1];
    float a2 = aloc[3 * m + 2];
    float w  = params[m];
    float s  = 0.5f / (w * w);
    float sp = -s * LOG2E;
    float q  = sp * (a0 * a0 + a1 * a1 + a2 * a2);
    A4[m] = make_float4(-2.0f * sp * a0, -2.0f * sp * a1, -2.0f * sp * a2, q);
    A2[m] = make_float2(sp, coeffs[m]);
}

// ---------------------------------------------------------------------------
// Kernel 2: main pair loop. Grid (256, CHUNKS) x 256 threads.
// Each thread owns 2 points (n, n+65536) and one anchor chunk of 512.
// Anchor params are loop-uniform -> compiler should emit s_load (scalar pipe),
// leaving VALU free for the 4-FMA + exp2 per pair.
// ---------------------------------------------------------------------------
__global__ __launch_bounds__(256, 8) void linear_potential_main(
    const float* __restrict__ xloc,
    const float4* __restrict__ A4,
    const float2* __restrict__ A2,
    float* __restrict__ out)
{
    const int tid = blockIdx.x * 256 + threadIdx.x;   // [0, 65536)
    const int n0  = tid;
    const int n1  = tid + (N_POINTS / 2);

    const float x0 = xloc[3 * n0 + 0];
    const float y0 = xloc[3 * n0 + 1];
    const float z0 = xloc[3 * n0 + 2];
    const float x1 = xloc[3 * n1 + 0];
    const float y1 = xloc[3 * n1 + 1];
    const float z1 = xloc[3 * n1 + 2];
    const float xs0 = x0 * x0 + y0 * y0 + z0 * z0;
    const float xs1 = x1 * x1 + y1 * y1 + z1 * z1;

    float acc0 = 0.0f;
    float acc1 = 0.0f;

    const int mbase = blockIdx.y * M_PER;
    #pragma unroll 4
    for (int mm = 0; mm < M_PER; ++mm) {
        const int m = mbase + mm;
        const float4 p = A4[m];
        const float2 t = A2[m];
        float arg0 = p.w + p.x * x0 + p.y * y0 + p.z * z0 + t.x * xs0;
        float arg1 = p.w + p.x * x1 + p.y * y1 + p.z * z1 + t.x * xs1;
        arg0 = fminf(arg0, 0.0f);
        arg1 = fminf(arg1, 0.0f);
        acc0 += t.y * __builtin_amdgcn_exp2f(arg0);
        acc1 += t.y * __builtin_amdgcn_exp2f(arg1);
    }

    atomicAdd(&out[n0], acc0);
    atomicAdd(&out[n1], acc1);
}

extern "C" void kernel_launch(void* const* d_in, const int* in_sizes, int n_in,
                              void* d_out, int out_size, void* d_ws, size_t ws_size,
                              hipStream_t stream) {
    const float* xloc   = (const float*)d_in[0];   // [131072,3]
    const float* aloc   = (const float*)d_in[1];   // [2048,3]
    const float* coeffs = (const float*)d_in[2];   // [2048]
    const float* params = (const float*)d_in[3];   // [2048]
    float* out = (float*)d_out;                    // [131072] f32

    float4* A4 = (float4*)d_ws;                                // 32 KiB
    float2* A2 = (float2*)((char*)d_ws + N_ANCHORS * sizeof(float4)); // +16 KiB

    // d_out is poisoned 0xAA before every timed call -> zero it (capturable).
    hipMemsetAsync(d_out, 0, N_POINTS * sizeof(float), stream);

    precompute_anchors<<<dim3(N_ANCHORS / 256), dim3(256), 0, stream>>>(
        aloc, coeffs, params, A4, A2);

    linear_potential_main<<<dim3((N_POINTS / 2) / 256, CHUNKS), dim3(256), 0, stream>>>(
        xloc, A4, A2, out);
}

// Round 2
// 107.319 us; speedup vs baseline: 1.4014x; 1.4014x over previous
//
#include <hip/hip_runtime.h>

#define N_POINTS  131072
#define N_ANCHORS 2048
#define CHUNKS    8
#define M_PER     (N_ANCHORS / CHUNKS)   // 256
#define LOG2E     1.4426950408889634f

typedef float v2f __attribute__((ext_vector_type(2)));

// ---------------------------------------------------------------------------
// Single fused kernel. Grid (256, CHUNKS) x 256 threads, 8192 waves = 8/SIMD.
// Each block:
//   1. folds its 256-anchor chunk's params into LDS (1 anchor/thread):
//        sp = -log2(e)/(2 w^2);  r = -2*sp*a;  q = sp*|a|^2
//        arg(n,m) = q + r.x_n + sp*|x_n|^2 ;  K = exp2(min(arg,0))
//   2. each thread owns 2 points (n, n+65536) packed in v2f lanes ->
//      v_pk_fma_f32 for the dot products; v_exp_f32 per lane.
//   3. atomicAdd partial sums (8 adds/output, out pre-zeroed by memset).
// ---------------------------------------------------------------------------
__global__ __launch_bounds__(256, 8) void linear_potential_main(
    const float* __restrict__ xloc,
    const float* __restrict__ aloc,
    const float* __restrict__ coeffs,
    const float* __restrict__ params,
    float* __restrict__ out)
{
    __shared__ float4 sA[M_PER];   // (r0, r1, r2, q)
    __shared__ float2 sB[M_PER];   // (sp, coeff)

    const int t     = threadIdx.x;
    const int mbase = blockIdx.y * M_PER;

    // --- anchor-chunk fold (1 anchor per thread, M_PER == blockDim) ---
    {
        const int m  = mbase + t;
        const float a0 = aloc[3 * m + 0];
        const float a1 = aloc[3 * m + 1];
        const float a2 = aloc[3 * m + 2];
        const float w  = params[m];
        const float s  = 0.5f / (w * w);
        const float sp = -s * LOG2E;
        sA[t] = make_float4(-2.0f * sp * a0, -2.0f * sp * a1, -2.0f * sp * a2,
                            sp * (a0 * a0 + a1 * a1 + a2 * a2));
        sB[t] = make_float2(sp, coeffs[m]);
    }
    __syncthreads();

    // --- per-thread point pair, packed in v2f lanes ---
    const int tid = blockIdx.x * 256 + t;     // [0, 65536)
    const int n0  = tid;
    const int n1  = tid + (N_POINTS / 2);

    const v2f xv = { xloc[3 * n0 + 0], xloc[3 * n1 + 0] };
    const v2f yv = { xloc[3 * n0 + 1], xloc[3 * n1 + 1] };
    const v2f zv = { xloc[3 * n0 + 2], xloc[3 * n1 + 2] };
    const v2f xs = xv * xv + yv * yv + zv * zv;

    v2f acc = { 0.0f, 0.0f };

    #pragma unroll 8
    for (int mm = 0; mm < M_PER; ++mm) {
        const float4 p  = sA[mm];
        const float2 tt = sB[mm];
        v2f arg = p.w + p.x * xv + p.y * yv + p.z * zv + tt.x * xs;
        arg.x = fminf(arg.x, 0.0f);
        arg.y = fminf(arg.y, 0.0f);
        v2f e = { __builtin_amdgcn_exp2f(arg.x), __builtin_amdgcn_exp2f(arg.y) };
        acc += tt.y * e;
    }

    atomicAdd(&out[n0], acc.x);
    atomicAdd(&out[n1], acc.y);
}

extern "C" void kernel_launch(void* const* d_in, const int* in_sizes, int n_in,
                              void* d_out, int out_size, void* d_ws, size_t ws_size,
                              hipStream_t stream) {
    const float* xloc   = (const float*)d_in[0];   // [131072,3]
    const float* aloc   = (const float*)d_in[1];   // [2048,3]
    const float* coeffs = (const float*)d_in[2];   // [2048]
    const float* params = (const float*)d_in[3];   // [2048]
    float* out = (float*)d_out;                    // [131072] f32

    // d_out is poisoned 0xAA before every timed call -> zero it (capturable).
    hipMemsetAsync(d_out, 0, N_POINTS * sizeof(float), stream);

    linear_potential_main<<<dim3((N_POINTS / 2) / 256, CHUNKS), dim3(256), 0, stream>>>(
        xloc, aloc, coeffs, params, out);
}

// Round 3
// 99.514 us; speedup vs baseline: 1.5113x; 1.0784x over previous
//
#include <hip/hip_runtime.h>

#define N_POINTS  131072
#define N_ANCHORS 2048
#define CHUNKS    16
#define M_PER     (N_ANCHORS / CHUNKS)   // 128 anchors per block
#define THREADS   256
#define PTS       4                      // points per thread
#define PT_STRIDE (N_POINTS / PTS)       // 32768
#define LOG2E     1.4426950408889634f

typedef float v2f __attribute__((ext_vector_type(2)));

// ---------------------------------------------------------------------------
// Grid (128, 16) x 256. 2048 blocks = 8 blocks/CU = 32 waves/CU (full).
// Each block: fold its 128-anchor chunk into LDS, then each thread evaluates
// 4 points x 128 anchors. Clamp dropped (see theory: error <= 5e-5).
//   arg(n,m) = q_m + r_m . x_n + sp_m*|x_n|^2 ;  K = exp2(arg)
// Very negative args (~ -3600 max) flush to 0 in v_exp_f32 -- no NaN risk.
// ---------------------------------------------------------------------------
__global__ __launch_bounds__(256, 8) void linear_potential_main(
    const float* __restrict__ xloc,
    const float* __restrict__ aloc,
    const float* __restrict__ coeffs,
    const float* __restrict__ params,
    float* __restrict__ out)
{
    __shared__ float4 sA[M_PER];   // (r0, r1, r2, q)
    __shared__ float2 sB[M_PER];   // (sp, coeff)

    const int t     = threadIdx.x;
    const int mbase = blockIdx.y * M_PER;

    if (t < M_PER) {
        const int m  = mbase + t;
        const float a0 = aloc[3 * m + 0];
        const float a1 = aloc[3 * m + 1];
        const float a2 = aloc[3 * m + 2];
        const float w  = params[m];
        const float sp = -(0.5f * LOG2E) / (w * w);
        sA[t] = make_float4(-2.0f * sp * a0, -2.0f * sp * a1, -2.0f * sp * a2,
                            sp * (a0 * a0 + a1 * a1 + a2 * a2));
        sB[t] = make_float2(sp, coeffs[m]);
    }
    __syncthreads();

    const int tid = blockIdx.x * THREADS + t;     // [0, 32768)
    const int n0 = tid;
    const int n1 = tid + PT_STRIDE;
    const int n2 = tid + 2 * PT_STRIDE;
    const int n3 = tid + 3 * PT_STRIDE;

    // pair a = {pt0, pt1}, pair b = {pt2, pt3}
    const v2f xa = { xloc[3 * n0 + 0], xloc[3 * n1 + 0] };
    const v2f ya = { xloc[3 * n0 + 1], xloc[3 * n1 + 1] };
    const v2f za = { xloc[3 * n0 + 2], xloc[3 * n1 + 2] };
    const v2f xb = { xloc[3 * n2 + 0], xloc[3 * n3 + 0] };
    const v2f yb = { xloc[3 * n2 + 1], xloc[3 * n3 + 1] };
    const v2f zb = { xloc[3 * n2 + 2], xloc[3 * n3 + 2] };

    const v2f ssa = __builtin_elementwise_fma(xa, xa,
                    __builtin_elementwise_fma(ya, ya, za * za));
    const v2f ssb = __builtin_elementwise_fma(xb, xb,
                    __builtin_elementwise_fma(yb, yb, zb * zb));

    v2f acca = { 0.0f, 0.0f };
    v2f accb = { 0.0f, 0.0f };

    #pragma unroll 8
    for (int mm = 0; mm < M_PER; ++mm) {
        const float4 p = sA[mm];
        const float2 c = sB[mm];
        const v2f pw = { p.w, p.w };
        const v2f px = { p.x, p.x };
        const v2f py = { p.y, p.y };
        const v2f pz = { p.z, p.z };
        const v2f sp = { c.x, c.x };
        const v2f cf = { c.y, c.y };

        v2f arga = __builtin_elementwise_fma(px, xa,
                   __builtin_elementwise_fma(py, ya,
                   __builtin_elementwise_fma(pz, za,
                   __builtin_elementwise_fma(sp, ssa, pw))));
        v2f argb = __builtin_elementwise_fma(px, xb,
                   __builtin_elementwise_fma(py, yb,
                   __builtin_elementwise_fma(pz, zb,
                   __builtin_elementwise_fma(sp, ssb, pw))));

        v2f ea = { __builtin_amdgcn_exp2f(arga.x), __builtin_amdgcn_exp2f(arga.y) };
        v2f eb = { __builtin_amdgcn_exp2f(argb.x), __builtin_amdgcn_exp2f(argb.y) };

        acca = __builtin_elementwise_fma(cf, ea, acca);
        accb = __builtin_elementwise_fma(cf, eb, accb);
    }

    atomicAdd(&out[n0], acca.x);
    atomicAdd(&out[n1], acca.y);
    atomicAdd(&out[n2], accb.x);
    atomicAdd(&out[n3], accb.y);
}

extern "C" void kernel_launch(void* const* d_in, const int* in_sizes, int n_in,
                              void* d_out, int out_size, void* d_ws, size_t ws_size,
                              hipStream_t stream) {
    const float* xloc   = (const float*)d_in[0];   // [131072,3]
    const float* aloc   = (const float*)d_in[1];   // [2048,3]
    const float* coeffs = (const float*)d_in[2];   // [2048]
    const float* params = (const float*)d_in[3];   // [2048]
    float* out = (float*)d_out;                    // [131072] f32

    // d_out is poisoned 0xAA before every timed call -> zero it (capturable).
    hipMemsetAsync(d_out, 0, N_POINTS * sizeof(float), stream);

    linear_potential_main<<<dim3(N_POINTS / (THREADS * PTS), CHUNKS),
                            dim3(THREADS), 0, stream>>>(
        xloc, aloc, coeffs, params, out);
}